// Round 10
// baseline (748.566 us; speedup 1.0000x reference)
//
#include <hip/hip_runtime.h>

#define NN 25600
#define EE 409600
#define BB 64
#define NGR 400
#define DD 128
#define HH 64
#define RR 32
#define EA 204800              // available (odd) edges
#define BPL 1600               // 128-edge blocks per label (worst case)

// workspace layout (float offsets)
#define OFF_AGGE   0
#define OFF_AGGO   1638400
#define OFF_NMASK  3276800
#define OFF_POOLF  3302400
#define OFF_POOLS  3304448
#define OFF_CNT    3306496
#define OFF_LCOUNT 3306560     // 4 uints
#define OFF_SEGKEY 3306568     // 64 u64 (8B-aligned)
#define OFF_CNT2   3306696     // 128 uints (graph x parity counters)
#define ZERO_END   3306824
#define OFF_H      3306824
#define OFF_NRA    4945224     // also overlays ELIST2 (consumed by k_edges before k_node writes)
#define OFF_BIAS1  5764424
#define OFF_ELIST  5772616     // 4*EA ints
// ELIST2: 128 buckets x 4096 ints at OFF_NRA; weight packs overlay AGGE (dead after k_node)

typedef short bf16x8 __attribute__((ext_vector_type(8)));
typedef float floatx4 __attribute__((ext_vector_type(4)));
#define MFMA16 __builtin_amdgcn_mfma_f32_16x16x32_bf16

// fast elu: hardware v_exp_f32; rel err ~2^-21, far inside absmax budget
__device__ __forceinline__ float eluf(float v){ return v > 0.f ? v : __expf(v) - 1.f; }

__device__ __forceinline__ void splitbf(float v, unsigned short& h, unsigned short& l){
  const unsigned u = __float_as_uint(v);
  h = (unsigned short)(u >> 16);
  const float hf = __uint_as_float(u & 0xFFFF0000u);
  l = (unsigned short)(__float_as_uint(v - hf) >> 16);
}

__device__ __forceinline__ unsigned long long packkey(float f, unsigned idx){
  unsigned u = __float_as_uint(f);
  u = (u & 0x80000000u) ? ~u : (u | 0x80000000u);
  return ((unsigned long long)u << 32) | (unsigned long long)(0xFFFFFFFFu - idx);
}

// ---------------- h = elu(x @ Wm1) ----------------
__global__ __launch_bounds__(256) void k_h(const float* __restrict__ x,
                                           const float* __restrict__ Wm1,
                                           float* __restrict__ h)
{
  __shared__ float xs[64][129];
  const int tid = threadIdx.x;
  const int n0 = blockIdx.x * 64;
  for (int idx = tid; idx < 64*128; idx += 256){
    int r = idx >> 7, c = idx & 127;
    xs[r][c] = x[(n0 + r)*DD + c];
  }
  __syncthreads();
  const int m = tid & 63, ng = tid >> 6;
  float4 acc[4];
  #pragma unroll
  for (int c = 0; c < 4; ++c) acc[c] = make_float4(0.f,0.f,0.f,0.f);
  for (int k = 0; k < 128; ++k){
    const float a = xs[m][k];
    const float* wr = Wm1 + k*64 + ng*16;
    #pragma unroll
    for (int c = 0; c < 4; ++c){
      const float4 w = *(const float4*)(wr + 4*c);
      acc[c].x += a*w.x; acc[c].y += a*w.y; acc[c].z += a*w.z; acc[c].w += a*w.w;
    }
  }
  float* hp = h + (n0 + m)*HH + ng*16;
  #pragma unroll
  for (int c = 0; c < 4; ++c){
    hp[4*c+0] = eluf(acc[c].x); hp[4*c+1] = eluf(acc[c].y);
    hp[4*c+2] = eluf(acc[c].z); hp[4*c+3] = eluf(acc[c].w);
  }
}

// ---------------- bucket ALL edges: block-local count -> reserve -> scatter ----------------
__global__ __launch_bounds__(256) void k_bucket(const int* __restrict__ ei,
                                                const int* __restrict__ y,
                                                unsigned* __restrict__ lcount,
                                                int* __restrict__ elist,
                                                unsigned* __restrict__ cnt2,
                                                int* __restrict__ elist2)
{
  __shared__ unsigned cl[128], bl[128], ol[128];
  __shared__ unsigned lc[4], lb[4], lo[4];
  const int tid = threadIdx.x;
  const int e0 = blockIdx.x * (EE/256);       // 1600 edges per block
  if (tid < 128){ cl[tid] = 0; ol[tid] = 0; }
  if (tid < 4){ lc[tid] = 0; lo[tid] = 0; }
  __syncthreads();
  int bk[7]; int ne = 0;
  for (int e = e0 + tid; e < e0 + EE/256; e += 256){
    const int d = ei[EE + e];
    const int g = d / NGR;
    const int bkt = g*2 + (e & 1);
    bk[ne++] = bkt;
    atomicAdd(&cl[bkt], 1u);
    if (e & 1) atomicAdd(&lc[y[g]], 1u);
  }
  __syncthreads();
  if (tid < 128 && cl[tid]) bl[tid] = atomicAdd(&cnt2[tid], cl[tid]);
  if (tid < 4 && lc[tid])   lb[tid] = atomicAdd(&lcount[tid], lc[tid]);
  __syncthreads();
  ne = 0;
  for (int e = e0 + tid; e < e0 + EE/256; e += 256){
    const int bkt = bk[ne++];
    const unsigned r = atomicAdd(&ol[bkt], 1u);
    elist2[bkt*4096 + (int)(bl[bkt] + r)] = e;
    if (e & 1){
      const int l = y[bkt >> 1];
      const unsigned r2 = atomicAdd(&lo[l], 1u);
      elist[l*EA + (int)(lb[l] + r2)] = e >> 1;
    }
  }
}

// ---------------- edge aggregation: drain pre-bucketed edges into LDS ----------------
__global__ __launch_bounds__(256) void k_edges(const int* __restrict__ ei,
                                               const float* __restrict__ h,
                                               const unsigned* __restrict__ cnt2,
                                               const int* __restrict__ elist2,
                                               float* __restrict__ aggE,
                                               float* __restrict__ aggO,
                                               float* __restrict__ nmask)
{
  __shared__ float acc[400*36];
  __shared__ unsigned char mk[400];
  const int b = blockIdx.x;
  const int g = b >> 2, p = (b >> 1) & 1, ch = b & 1;
  const int tid = threadIdx.x;
  const int nlo = g * NGR;
  for (int i = tid; i < 400*36; i += 256) acc[i] = 0.f;
  if (tid < 400) mk[tid] = 0;
  __syncthreads();
  const int bkt = g*2 + p;
  const int n = (int)cnt2[bkt];
  const int j0 = tid >> 3, c8 = tid & 7;
  const bool domask = (p == 0) && (ch == 0) && (c8 == 0);
  for (int j = j0; j < n; j += 32){
    const int e = elist2[bkt*4096 + j];
    const int s = ei[e];
    const int d = ei[EE + e] - nlo;
    const float4 v = *(const float4*)(h + s*HH + ch*32 + c8*4);
    float* ap = &acc[d*36 + c8*4];
    atomicAdd(ap+0, v.x); atomicAdd(ap+1, v.y);
    atomicAdd(ap+2, v.z); atomicAdd(ap+3, v.w);
    if (domask){ mk[s - nlo] = 1; mk[d] = 1; }
  }
  __syncthreads();
  float* agg = p ? aggO : aggE;
  for (int idx = tid; idx < 400*32; idx += 256){
    const int d = idx >> 5, col = idx & 31;
    agg[(nlo + d)*HH + ch*32 + col] = acc[d*36 + col];
  }
  if (p == 0 && ch == 0){
    for (int idx = tid; idx < 400; idx += 256) nmask[nlo + idx] = (float)mk[idx];
  }
}

// ---------------- node reps + pooled sums (LDS-reduced pools) ----------------
__global__ __launch_bounds__(256) void k_node(const float* __restrict__ h,
                                              const float* __restrict__ aggE,
                                              const float* __restrict__ aggO,
                                              const float* __restrict__ Wm2,
                                              const float* __restrict__ nmask,
                                              float* __restrict__ nra,
                                              float* __restrict__ poolF,
                                              float* __restrict__ poolS,
                                              float* __restrict__ cntArr)
{
  __shared__ float hs[8][64], ae[8][64], ao[8][64];
  __shared__ float wm[64][32];
  __shared__ float rf[8][32], rs[8][32], rc[8];
  const int tid = threadIdx.x;
  const int n0 = blockIdx.x * 8;
  for (int idx = tid; idx < 512; idx += 256){
    int i = idx >> 6, k = idx & 63, n = n0 + i;
    hs[i][k] = h[n*HH + k];
    ae[i][k] = aggE[n*HH + k];
    ao[i][k] = aggO[n*HH + k];
  }
  for (int idx = tid; idx < 2048; idx += 256) wm[idx >> 5][idx & 31] = Wm2[idx];
  __syncthreads();
  const int i = tid >> 5, r = tid & 31;
  const int n = n0 + i;
  float aF = 0.f, aS = 0.f, aA = 0.f;
  #pragma unroll 4
  for (int k = 0; k < 64; ++k){
    const float th = hs[i][k], te = ae[i][k], to = ao[i][k], w = wm[k][r];
    aF += (th + te + to) * w;
    aS += (th + te) * w;
    aA += (th + to) * w;
  }
  aF = eluf(aF); aS = eluf(aS); aA = eluf(aA);
  nra[n*RR + r] = aA;
  const float msk = nmask[n];
  rf[i][r] = aF;
  rs[i][r] = (msk != 0.f) ? aS : 0.f;
  if (r == 0) rc[i] = (msk != 0.f) ? 1.f : 0.f;
  __syncthreads();
  const int g = n0 / NGR;
  if (tid < 32){
    float sf = 0.f, ss = 0.f;
    #pragma unroll
    for (int k = 0; k < 8; ++k){ sf += rf[k][tid]; ss += rs[k][tid]; }
    atomicAdd(&poolF[g*RR + tid], sf);
    atomicAdd(&poolS[g*RR + tid], ss);
  } else if (tid == 32){
    float sc = 0.f;
    #pragma unroll
    for (int k = 0; k < 8; ++k) sc += rc[k];
    atomicAdd(&cntArr[g], sc);
  }
}

// ---------------- pack all MLP weights into MFMA fragment hi/lo bf16 ----------------
// (same layout doubles as W^T A-fragments: A[m=lane&15][k=(lane>>4)*8+j] = W[k][col])
__global__ __launch_bounds__(256) void k_pack(const float* __restrict__ W1,
                                              const float* __restrict__ W2,
                                              const float* __restrict__ W3,
                                              const float* __restrict__ We1,
                                              const float* __restrict__ We2,
                                              unsigned short* __restrict__ pk)
{
  const int t = blockIdx.x*4 + (threadIdx.x >> 6);   // 0..239
  const int L = threadIdx.x & 63;
  int tl, KT, N; const float* W;
  if (t < 32)      { tl = t;      KT = 2; N = 256; W = W1; }
  else if (t < 96) { tl = t-32;   KT = 8; N = 128; W = W2; }
  else if (t < 112){ tl = t-96;   KT = 4; N = 64;  W = W3; }
  else if (t < 176){ int u = t-112; int lb = u >> 4; tl = u & 15; KT = 2; N = 128; W = We1 + lb*16384; }
  else             { int u = t-176; int lb = u >> 4; tl = u & 15; KT = 4; N = 64;  W = We2 + lb*8192; }
  const int nt = tl / KT, kt = tl % KT;
  const int krow = kt*32 + (L >> 4)*8;
  const int col  = nt*16 + (L & 15);
  unsigned short* dh = pk + (unsigned)t*1024 + L*8;
  unsigned short* dl = dh + 512;
  #pragma unroll
  for (int j = 0; j < 8; ++j){
    const float v = W[(krow + j)*N + col];
    unsigned short h, l2;
    splitbf(v, h, l2);
    dh[j] = h; dl[j] = l2;
  }
}

// ---------------- per-graph diff and explainer bias ----------------
__global__ __launch_bounds__(128) void k_graph(const float* __restrict__ poolF,
                                               const float* __restrict__ poolS,
                                               const float* __restrict__ cnt,
                                               const float* __restrict__ Wg,
                                               const int* __restrict__ y,
                                               const float* __restrict__ We1,
                                               const float* __restrict__ be1,
                                               float* __restrict__ bias1)
{
  __shared__ float pd[32];
  __shared__ float dg[64];
  const int g = blockIdx.x, tid = threadIdx.x;
  if (tid < 32){
    const float c = cnt[g];
    const float pf = poolF[g*RR + tid] * (1.0f/400.0f);
    const float ps = poolS[g*RR + tid] / fmaxf(c, 1.0f);
    pd[tid] = pf - ps;
  }
  __syncthreads();
  if (tid < 64){
    float a = 0.f;
    #pragma unroll
    for (int r = 0; r < 32; ++r) a += pd[r] * Wg[r*64 + tid];
    dg[tid] = a;
  }
  __syncthreads();
  const int l = y[g];
  float acc = be1[l*128 + tid];
  #pragma unroll 8
  for (int j = 0; j < 64; ++j) acc += dg[j] * We1[l*16384 + (64 + j)*128 + tid];
  bias1[g*128 + tid] = acc;
}

// ---------------- k_mlp helpers (weights-as-A transposed dataflow) ----------------
// acc[mt] covers D[feat=mt*16+q*4+r][edge=lane&15]
template<int MT, int KT>
__device__ __forceinline__ void runLayer(floatx4 (&acc)[MT],
                                         const bf16x8 (&bx)[KT*2],
                                         const unsigned short* __restrict__ W,
                                         int lane)
{
  #pragma unroll
  for (int mt = 0; mt < MT; ++mt){
    #pragma unroll
    for (int kt = 0; kt < KT; ++kt){
      const unsigned short* p = W + (mt*KT + kt)*1024 + lane*8;
      const bf16x8 wh = *(const bf16x8*)p;
      const bf16x8 wl = *(const bf16x8*)(p + 512);
      acc[mt] = MFMA16(wh, bx[kt*2+0], acc[mt], 0, 0, 0);
      acc[mt] = MFMA16(wl, bx[kt*2+0], acc[mt], 0, 0, 0);
      acc[mt] = MFMA16(wh, bx[kt*2+1], acc[mt], 0, 0, 0);
    }
  }
}

template<int MT>
__device__ __forceinline__ void actElu(floatx4 (&acc)[MT])
{
  #pragma unroll
  for (int mt = 0; mt < MT; ++mt)
    #pragma unroll
    for (int r = 0; r < 4; ++r)
      acc[mt][r] = eluf(acc[mt][r]);
}

// C-layout (feat = mt*16+q*4+r) -> next-layer B-frags (lane (e,q) holds feats kt*32+q*8+j)
template<int MTS, int KTN>
__device__ __forceinline__ void repack(const floatx4 (&acc)[MTS],
                                       bf16x8 (&out)[KTN*2],
                                       int lane)
{
  static_assert(MTS == 2*KTN, "feat count mismatch");
  const int e = lane & 15, q = lane >> 4;
  const int qs = (q & 1) * 2;
  const bool hi2 = (q >> 1) != 0;
  #pragma unroll
  for (int kt = 0; kt < KTN; ++kt){
    bf16x8 bh, bl;
    #pragma unroll
    for (int j = 0; j < 8; ++j){
      const int src = e + 16*(qs + (j >> 2));
      const float v0 = __shfl(acc[2*kt  ][j & 3], src);
      const float v1 = __shfl(acc[2*kt+1][j & 3], src);
      const float v = hi2 ? v1 : v0;
      unsigned short h, l2;
      splitbf(v, h, l2);
      bh[j] = (short)h; bl[j] = (short)l2;
    }
    out[kt*2+0] = bh; out[kt*2+1] = bl;
  }
}

template<int MT>
__device__ __forceinline__ void initBias(floatx4 (&acc)[MT], const float* __restrict__ b, int q)
{
  #pragma unroll
  for (int mt = 0; mt < MT; ++mt)
    #pragma unroll
    for (int r = 0; r < 4; ++r)
      acc[mt][r] = b[mt*16 + q*4 + r];
}

// ---------------- fused per-edge MLP: weights in LDS (3 stage phases), activations in regs ----------------
__global__ __launch_bounds__(512, 2) void k_mlp(const float* __restrict__ nra,
                                             const int* __restrict__ ei,
                                             const unsigned short* __restrict__ pk,
                                             const float* __restrict__ b1,
                                             const float* __restrict__ b2,
                                             const float* __restrict__ b3,
                                             const float* __restrict__ be2,
                                             const float* __restrict__ We3,
                                             const float* __restrict__ be3,
                                             const float* __restrict__ bias1,
                                             const int* __restrict__ elist,
                                             const unsigned* __restrict__ lcount,
                                             float* __restrict__ probs,
                                             unsigned long long* __restrict__ segkey)
{
  __shared__ unsigned short Bst[65536];   // 128 KB weight stage
  const int l  = blockIdx.x / BPL;
  const int bt = blockIdx.x % BPL;
  const unsigned cnt = lcount[l];
  if ((unsigned)(bt*128) >= cnt) return;
  const int tid = threadIdx.x;
  const int wv = tid >> 6, lane = tid & 63;
  const int e = lane & 15, q = lane >> 4;
  const int base = bt*128 + wv*16;
  int mm = base + e;
  const bool valid = (unsigned)mm < cnt;
  if (!valid) mm = (int)cnt - 1;
  const int i  = elist[l*EA + mm];
  const int ee = 2*i + 1;
  const int s  = ei[ee], d = ei[EE + ee];
  const int g  = s / NGR;

  // in0 B-frags: kt0 <-> nr[src] (feats 0..31), kt1 <-> nr[dst]
  bf16x8 x0[4];
  {
    const float* ps = nra + s*RR + q*8;
    const float* pd = nra + d*RR + q*8;
    float vs[8], vd[8];
    *(float4*)&vs[0] = *(const float4*)ps; *(float4*)&vs[4] = *(const float4*)(ps+4);
    *(float4*)&vd[0] = *(const float4*)pd; *(float4*)&vd[4] = *(const float4*)(pd+4);
    bf16x8 h0, l0, h1, l1;
    #pragma unroll
    for (int j = 0; j < 8; ++j){
      unsigned short h, l2;
      splitbf(vs[j], h, l2); h0[j] = (short)h; l0[j] = (short)l2;
      splitbf(vd[j], h, l2); h1[j] = (short)h; l1[j] = (short)l2;
    }
    x0[0] = h0; x0[1] = l0; x0[2] = h1; x0[3] = l1;
  }

  // ---- phase 1: W1 (64 KB) ----
  for (int idx = tid; idx < 32*128; idx += 512)
    *(int4*)(Bst + idx*8) = *(const int4*)(pk + idx*8);
  __syncthreads();
  floatx4 a1[16];
  initBias<16>(a1, b1, q);
  runLayer<16,2>(a1, x0, Bst, lane);
  actElu<16>(a1);
  bf16x8 x1[16];
  repack<16,8>(a1, x1, lane);
  __syncthreads();

  // ---- phase 2: W2 (128 KB) ----
  for (int idx = tid; idx < 64*128; idx += 512)
    *(int4*)(Bst + idx*8) = *(const int4*)(pk + 32*1024 + idx*8);
  __syncthreads();
  floatx4 a2[8];
  initBias<8>(a2, b2, q);
  runLayer<8,8>(a2, x1, Bst, lane);
  actElu<8>(a2);
  bf16x8 x2[8];
  repack<8,4>(a2, x2, lane);
  __syncthreads();

  // ---- phase 3: W3 + We1[l] + We2[l] (96 KB) ----
  {
    const unsigned short* pk4 = pk + (unsigned)(112 + l*16)*1024;
    const unsigned short* pk5 = pk + (unsigned)(176 + l*16)*1024;
    for (int idx = tid; idx < 16*128; idx += 512){
      *(int4*)(Bst + idx*8)         = *(const int4*)(pk + 96*1024 + idx*8);
      *(int4*)(Bst + 16384 + idx*8) = *(const int4*)(pk4 + idx*8);
      *(int4*)(Bst + 32768 + idx*8) = *(const int4*)(pk5 + idx*8);
    }
  }
  __syncthreads();

  // L3 (no elu)
  floatx4 a3[4];
  initBias<4>(a3, b3, q);
  runLayer<4,4>(a3, x2, Bst, lane);
  bf16x8 x3[4];
  repack<4,2>(a3, x3, lane);

  // L4: per-graph bias init (gather by edge's graph)
  floatx4 a4[8];
  {
    const float* bp = bias1 + g*128;
    #pragma unroll
    for (int mt = 0; mt < 8; ++mt)
      #pragma unroll
      for (int r = 0; r < 4; ++r)
        a4[mt][r] = bp[mt*16 + q*4 + r];
  }
  runLayer<8,2>(a4, x3, Bst + 16384, lane);
  actElu<8>(a4);
  bf16x8 x4[8];
  repack<8,4>(a4, x4, lane);

  // L5
  floatx4 a5[4];
  initBias<4>(a5, be2 + l*64, q);
  runLayer<4,4>(a5, x4, Bst + 32768, lane);
  actElu<4>(a5);

  // L6: dot with We3[l] + reduce over q-groups
  float sdot = 0.f;
  {
    const float* w3 = We3 + l*64;
    #pragma unroll
    for (int mt = 0; mt < 4; ++mt)
      #pragma unroll
      for (int r = 0; r < 4; ++r)
        sdot += a5[mt][r] * w3[mt*16 + q*4 + r];
  }
  sdot += __shfl_xor(sdot, 16);
  sdot += __shfl_xor(sdot, 32);
  if (valid && q == 0){
    const float sc = sdot + be3[l];
    probs[i] = sc;
    atomicMax(&segkey[g], packkey(sc, (unsigned)i));
  }
}

// ---------------- finalize outputs ----------------
__global__ void k_final(const unsigned long long* __restrict__ segkey, float* __restrict__ out)
{
  const int g = threadIdx.x;
  if (g < BB){
    const unsigned long long key = segkey[g];
    const unsigned u = (unsigned)(key >> 32);
    const float mx = (u & 0x80000000u) ? __uint_as_float(u & 0x7FFFFFFFu)
                                       : __uint_as_float(~u);
    const unsigned idx = 0xFFFFFFFFu - (unsigned)(key & 0xFFFFFFFFull);
    out[EA + g]        = mx;
    out[EA + BB + g]   = (float)idx;
    out[EA + 2*BB + g] = (float)g;
  }
}

extern "C" void kernel_launch(void* const* d_in, const int* in_sizes, int n_in,
                              void* d_out, int out_size, void* d_ws, size_t ws_size,
                              hipStream_t stream)
{
  (void)in_sizes; (void)n_in; (void)out_size; (void)ws_size;
  const float* x   = (const float*)d_in[0];
  const int*   ei  = (const int*)  d_in[1];
  const int*   y   = (const int*)  d_in[3];
  const float* Wm1 = (const float*)d_in[5];
  const float* Wm2 = (const float*)d_in[6];
  const float* Wg  = (const float*)d_in[7];
  const float* W1  = (const float*)d_in[8];
  const float* b1  = (const float*)d_in[9];
  const float* W2  = (const float*)d_in[10];
  const float* b2  = (const float*)d_in[11];
  const float* W3  = (const float*)d_in[12];
  const float* b3  = (const float*)d_in[13];
  const float* We1 = (const float*)d_in[14];
  const float* be1 = (const float*)d_in[15];
  const float* We2 = (const float*)d_in[16];
  const float* be2 = (const float*)d_in[17];
  const float* We3 = (const float*)d_in[18];
  const float* be3 = (const float*)d_in[19];

  float* wsf = (float*)d_ws;
  float* AGGE   = wsf + OFF_AGGE;
  float* AGGO   = wsf + OFF_AGGO;
  float* NMASK  = wsf + OFF_NMASK;
  float* POOLF  = wsf + OFF_POOLF;
  float* POOLS  = wsf + OFF_POOLS;
  float* CNT    = wsf + OFF_CNT;
  unsigned* LCOUNT = (unsigned*)(wsf + OFF_LCOUNT);
  unsigned long long* SEGKEY = (unsigned long long*)(wsf + OFF_SEGKEY);
  unsigned* CNT2 = (unsigned*)(wsf + OFF_CNT2);
  float* Hbuf   = wsf + OFF_H;
  float* NRA    = wsf + OFF_NRA;
  float* BIAS1  = wsf + OFF_BIAS1;
  int*   ELIST  = (int*)(wsf + OFF_ELIST);
  int*   ELIST2 = (int*)(wsf + OFF_NRA);    // overlays NRA; consumed before k_node writes NRA
  unsigned short* PK = (unsigned short*)(wsf + OFF_AGGE);  // overlays AGGE, written after k_node
  float* out = (float*)d_out;

  hipMemsetAsync(wsf + OFF_POOLF, 0, (size_t)(ZERO_END - OFF_POOLF) * sizeof(float), stream);

  k_h     <<<NN/64,   256, 0, stream>>>(x, Wm1, Hbuf);
  k_bucket<<<256,     256, 0, stream>>>(ei, y, LCOUNT, ELIST, CNT2, ELIST2);
  k_edges <<<BB*4,    256, 0, stream>>>(ei, Hbuf, CNT2, ELIST2, AGGE, AGGO, NMASK);
  k_node  <<<NN/8,    256, 0, stream>>>(Hbuf, AGGE, AGGO, Wm2, NMASK, NRA, POOLF, POOLS, CNT);
  k_pack  <<<60,      256, 0, stream>>>(W1, W2, W3, We1, We2, PK);
  k_graph <<<BB,      128, 0, stream>>>(POOLF, POOLS, CNT, Wg, y, We1, be1, BIAS1);
  k_mlp   <<<4*BPL,   512, 0, stream>>>(NRA, ei, PK, b1, b2, b3, be2, We3, be3,
                                        BIAS1, ELIST, LCOUNT, out, SEGKEY);
  k_final <<<1,        64, 0, stream>>>(SEGKEY, out);
}